// Round 13
// baseline (186.132 us; speedup 1.0000x reference)
//
#include <hip/hip_runtime.h>
#include <cstdint>
#include <cstddef>

#define NTOK 2048
#define DMODEL 1024
#define HD 64
#define MROWS 8192

using f16x8  = __attribute__((ext_vector_type(8))) _Float16;
using f16x4  = __attribute__((ext_vector_type(4))) _Float16;
using f32x4  = __attribute__((ext_vector_type(4))) float;
using f32x16 = __attribute__((ext_vector_type(16))) float;
using u16x8  = __attribute__((ext_vector_type(8))) unsigned short;
using u32x4  = __attribute__((ext_vector_type(4))) unsigned int;

#define Z16 {0.f,0.f,0.f,0.f,0.f,0.f,0.f,0.f,0.f,0.f,0.f,0.f,0.f,0.f,0.f,0.f}

__device__ __forceinline__ unsigned pkf16(float a, float b) {
  return __builtin_bit_cast(unsigned, __builtin_amdgcn_cvt_pkrtz(a, b));
}
__device__ __forceinline__ void plswap(unsigned &a, unsigned &b) {
  auto r = __builtin_amdgcn_permlane32_swap(a, b, false, false);
  a = r[0]; b = r[1];
}
// raw v_exp_f32: args always <= 0; flush-to-zero below -126 is correct for
// softmax tails.
__device__ __forceinline__ float fexp2(float x) {
  return __builtin_amdgcn_exp2f(x);
}

// ---------------------------------------------------------------------------
// f32 -> f16 convert (x)
// ---------------------------------------------------------------------------
__global__ __launch_bounds__(256) void cvt_f32_f16(const float* __restrict__ in,
                                                   _Float16* __restrict__ out,
                                                   int n4, float scale) {
  int idx = blockIdx.x * 256 + threadIdx.x;
  if (idx < n4) {
    float4 v = reinterpret_cast<const float4*>(in)[idx];
    f16x4 o;
    o.x = (_Float16)(v.x * scale); o.y = (_Float16)(v.y * scale);
    o.z = (_Float16)(v.z * scale); o.w = (_Float16)(v.w * scale);
    reinterpret_cast<f16x4*>(out)[idx] = o;
  }
}

// both weight matrices in one launch; log2(e) folded into Wq
__global__ __launch_bounds__(256) void cvt_w(const float* __restrict__ Wk,
                                             const float* __restrict__ Wq,
                                             _Float16* __restrict__ Wkb,
                                             _Float16* __restrict__ Wqb) {
  const int idx = blockIdx.x * 256 + threadIdx.x;
  const float* in = blockIdx.y ? Wq : Wk;
  _Float16* out = blockIdx.y ? Wqb : Wkb;
  const float scale = blockIdx.y ? 1.4426950408889634f : 1.0f;
  float4 v = reinterpret_cast<const float4*>(in)[idx];
  f16x4 o;
  o.x = (_Float16)(v.x * scale); o.y = (_Float16)(v.y * scale);
  o.z = (_Float16)(v.z * scale); o.w = (_Float16)(v.w * scale);
  reinterpret_cast<f16x4*>(out)[idx] = o;
}

// ---------------------------------------------------------------------------
// f16 MFMA GEMM: Y[m][o] = sum_k X[m][k] * W[o][k]  (NT), Y stored f16.
// ---------------------------------------------------------------------------
#define GLDS16(g, l) __builtin_amdgcn_global_load_lds(                      \
    (const __attribute__((address_space(1))) void*)(g),                     \
    (__attribute__((address_space(3))) void*)(l), 16, 0, 0)

__global__ __launch_bounds__(256) void gemm_f16(
    const _Float16* __restrict__ X,
    const _Float16* __restrict__ Wk,
    const _Float16* __restrict__ Wq,
    _Float16* __restrict__ Kb,
    _Float16* __restrict__ Qb) {
  const _Float16* __restrict__ W = blockIdx.z ? Wq : Wk;
  _Float16* __restrict__ Y = blockIdx.z ? Qb : Kb;

  __shared__ _Float16 As[2][128 * 32];
  __shared__ _Float16 Bs[2][128 * 32];

  const int tid = threadIdx.x;
  const int lane = tid & 63;
  const int w = tid >> 6;
  const int m0 = blockIdx.x * 128;
  const int o0 = blockIdx.y * 128;

  const int srow = w * 32 + (lane >> 2);
  const int scol = (lane & 3) * 8;
  const _Float16* xsrc = X + (size_t)(m0 + srow) * DMODEL + scol;
  const _Float16* wsrc = W + (size_t)(o0 + srow) * DMODEL + scol;

  const int wr = w >> 1, wc = w & 1;
  const int arow = lane & 15, kg = lane >> 4;

  f32x4 zero = {0.f, 0.f, 0.f, 0.f};
  f32x4 acc[4][4];
#pragma unroll
  for (int mi = 0; mi < 4; ++mi)
#pragma unroll
    for (int ni = 0; ni < 4; ++ni) acc[mi][ni] = zero;

  GLDS16(xsrc,               &As[0][(w * 32) * 32]);
  GLDS16(xsrc + 16 * DMODEL, &As[0][(w * 32 + 16) * 32]);
  GLDS16(wsrc,               &Bs[0][(w * 32) * 32]);
  GLDS16(wsrc + 16 * DMODEL, &Bs[0][(w * 32 + 16) * 32]);

  for (int kt = 0; kt < 32; ++kt) {
    __syncthreads();
    if (kt + 1 < 32) {
      const int ko = (kt + 1) * 32;
      const int bn = (kt + 1) & 1;
      GLDS16(xsrc + ko,               &As[bn][(w * 32) * 32]);
      GLDS16(xsrc + ko + 16 * DMODEL, &As[bn][(w * 32 + 16) * 32]);
      GLDS16(wsrc + ko,               &Bs[bn][(w * 32) * 32]);
      GLDS16(wsrc + ko + 16 * DMODEL, &Bs[bn][(w * 32 + 16) * 32]);
    }
    const int buf = kt & 1;
    f16x8 af[4], bfr[4];
#pragma unroll
    for (int mi = 0; mi < 4; ++mi)
      af[mi] = *reinterpret_cast<const f16x8*>(
          &As[buf][(wr * 64 + mi * 16 + arow) * 32 + kg * 8]);
#pragma unroll
    for (int ni = 0; ni < 4; ++ni)
      bfr[ni] = *reinterpret_cast<const f16x8*>(
          &Bs[buf][(wc * 64 + ni * 16 + arow) * 32 + kg * 8]);
#pragma unroll
    for (int mi = 0; mi < 4; ++mi)
#pragma unroll
      for (int ni = 0; ni < 4; ++ni)
        acc[mi][ni] = __builtin_amdgcn_mfma_f32_16x16x32_f16(
            af[mi], bfr[ni], acc[mi][ni], 0, 0, 0);
  }

#pragma unroll
  for (int mi = 0; mi < 4; ++mi) {
#pragma unroll
    for (int ni = 0; ni < 4; ++ni) {
#pragma unroll
      for (int r = 0; r < 4; ++r) {
        const int m = m0 + wr * 64 + mi * 16 + kg * 4 + r;
        const int o = o0 + wc * 64 + ni * 16 + arow;
        Y[(size_t)m * DMODEL + o] = (_Float16)acc[mi][ni][r];
      }
    }
  }
}

// ---------------------------------------------------------------------------
// Combined pack kernel (grid.y: 0 = pack Q rows, 1 = pack K transposed).
// y=0: Qp[bh][rt(32-row tiles)][ks][lane][8]  = Q_head[rt*32+(l&31)][ks*16+(l>>5)*8+e]
// y=1: KTp[bh][jt][ds][ks][lane][8] = K_head[jt*64+ks*16+(l>>5)*8+e][ds*32+(l&31)]
// ---------------------------------------------------------------------------
__global__ __launch_bounds__(256) void pack_qkt(
    const _Float16* __restrict__ Qb,
    const _Float16* __restrict__ Kb,
    _Float16* __restrict__ Qp,
    _Float16* __restrict__ KTp) {
  const int blk = blockIdx.x;
  const int bh = blk >> 5;
  const int t64 = blk & 31;
  const int b = bh >> 4, h = bh & 15;
  const int tid = threadIdx.x;
  const _Float16* Src = blockIdx.y ? Kb : Qb;

  __shared__ _Float16 t[64][72];
#pragma unroll
  for (int rr = 0; rr < 2; ++rr) {
    const int c = tid + rr * 256;
    const int jr = c >> 3, dcol = (c & 7) * 8;
    *reinterpret_cast<f16x8*>(&t[jr][dcol]) =
        *reinterpret_cast<const f16x8*>(
            &Src[(size_t)(b * NTOK + t64 * 64 + jr) * DMODEL + h * HD + dcol]);
  }
  __syncthreads();
  if (blockIdx.y == 0) {
#pragma unroll
    for (int rr = 0; rr < 2; ++rr) {
      const int cI = tid + rr * 256;   // (rs,ks,l)
      const int rs = cI >> 8, ks = (cI >> 6) & 3, l = cI & 63;
      f16x8 v = *reinterpret_cast<const f16x8*>(
          &t[rs * 32 + (l & 31)][ks * 16 + (l >> 5) * 8]);
      const size_t ch = ((size_t)(bh * 64 + t64 * 2 + rs) * 4 + ks) * 512 + l * 8;
      *reinterpret_cast<f16x8*>(&Qp[ch]) = v;
    }
  } else {
#pragma unroll
    for (int rr = 0; rr < 2; ++rr) {
      const int cI = tid + rr * 256;   // (ds,ks,l)
      const int ds = cI >> 8, ks = (cI >> 6) & 3, l = cI & 63;
      const int col = ds * 32 + (l & 31);
      const int row0 = ks * 16 + (l >> 5) * 8;
      f16x8 v;
#pragma unroll
      for (int e = 0; e < 8; ++e) v[e] = t[row0 + e][col];
      const size_t ch = (((size_t)(bh * 32 + t64) * 2 + ds) * 4 + ks) * 512 + l * 8;
      *reinterpret_cast<f16x8*>(&KTp[ch]) = v;
    }
  }
}

// ---------------------------------------------------------------------------
// Swapped-operand MFMA flash attention, SPLIT-J (flash merge).
// r12 lesson: occupancy was grid-capped (1024 blocks = 4 waves/SIMD). Here
// each wave handles 32 i-rows x HALF the j-range: block = 64 i-rows,
// waves {i_sub = w&1, jh = w>>1}; grid 2048 blocks -> 8192 waves.
// Inner loop identical to r12 (j-tile=32, in-place exp2, defer-max THR=8
// with LDS-routed per-row rescale, cvt_pkrtz+permlane32_swap repack).
// End merge (standard flash combine): m*=max(mA,mB);
// O* = OA*2^(mA-m*) + OB*2^(mB-m*); ls* likewise; out = O*/ls*.
// Wave B scales its O into LDS (lane-consecutive, conflict-free), one
// barrier, wave A adds/divides/stores.
// ---------------------------------------------------------------------------
__global__ __launch_bounds__(256, 3) void attn_mfma(
    const _Float16* __restrict__ Kb,
    const _Float16* __restrict__ Qp,
    const _Float16* __restrict__ KTp,
    float* __restrict__ out) {
  const int bid = blockIdx.x;
  const int myid = (bid & 7) * 256 + (bid >> 3);   // 2048 blocks, bijective
  const int bh = myid >> 5;                        // 32 blocks per head
  const int itile = myid & 31;
  const int b = bh >> 4, h = bh & 15;
  const int tid = threadIdx.x, lane = tid & 63, w = tid >> 6;
  const int l31 = lane & 31;
  const int hi = lane >> 5;
  const int hi8 = hi * 8;
  const int i_sub = w & 1;                         // which 32-row i-block
  const int jh = w >> 1;                           // which j-half
  const int i0 = itile * 64 + i_sub * 32;

  const _Float16* Kh   = Kb + (size_t)b * NTOK * DMODEL + h * HD;
  const _Float16* qpp  = Qp  + (size_t)bh * 131072 + lane * 8;
  const _Float16* ktpp = KTp + (size_t)bh * 131072 + lane * 8;

  __shared__ float scl[4][32];       // per-wave rescale routing line
  __shared__ float mM[2][2][32];     // [i_sub][jh][row] running max
  __shared__ float lsM[2][2][32];    // [i_sub][jh][row] row sum
  __shared__ float obuf[2][32][64];  // wave-B scaled O: [i_sub][reg][lane]

  // B-frags of K_i for QK^T (one-time, uncoalesced but tiny)
  f16x8 kbf[4];
#pragma unroll
  for (int ks = 0; ks < 4; ++ks)
    kbf[ks] = *reinterpret_cast<const f16x8*>(
        &Kh[(size_t)(i0 + l31) * DMODEL + ks * 16 + hi8]);

  const f32x16 z16v = Z16;
  f32x16 o0 = z16v, o1 = z16v;
  float mreg = -1e30f, ls = 0.f;

  const int jt0 = jh * 32;
  for (int jt = jt0; jt < jt0 + 32; ++jt) {
    // ---- Q fragments for this 32-j tile ----
    f16x8 q[4];
#pragma unroll
    for (int ks = 0; ks < 4; ++ks)
      q[ks] = *reinterpret_cast<const f16x8*>(qpp + ((size_t)jt * 4 + ks) * 512);

    // ---- QK^T: S^T(32j x 32i), lane holds col i=l31, 16 j's in regs ----
    f32x16 s = z16v;
    __builtin_amdgcn_s_setprio(1);
#pragma unroll
    for (int ks = 0; ks < 4; ++ks)
      s = __builtin_amdgcn_mfma_f32_32x32x16_f16(q[ks], kbf[ks], s, 0, 0, 0);
    __builtin_amdgcn_s_setprio(0);

    // ---- KT fragments (independent of softmax; latency hidden under it) ----
    f16x8 kt0[2], kt1[2];
    {
      const size_t base = ((size_t)(jt >> 1) * 8 + (size_t)(jt & 1) * 2) * 512;
#pragma unroll
      for (int kk = 0; kk < 2; ++kk) {
        kt0[kk] = *reinterpret_cast<const f16x8*>(ktpp + base + (size_t)kk * 512);
        kt1[kk] = *reinterpret_cast<const f16x8*>(ktpp + base + (size_t)(4 + kk) * 512);
      }
    }

    // ---- row max (16 j's here + 16 in partner half) ----
    float m0 = fmaxf(s[0], s[4]);
    float m1 = fmaxf(s[1], s[5]);
    float m2 = fmaxf(s[2], s[6]);
    float m3 = fmaxf(s[3], s[7]);
#pragma unroll
    for (int r = 8; r < 16; r += 4) {
      m0 = fmaxf(m0, s[r]);
      m1 = fmaxf(m1, s[r + 1]);
      m2 = fmaxf(m2, s[r + 2]);
      m3 = fmaxf(m3, s[r + 3]);
    }
    float pm = fmaxf(fmaxf(m0, m1), fmaxf(m2, m3));
    pm = fmaxf(pm, __shfl_xor(pm, 32));

    // ---- defer-max rescale (rare; per-row factor routed via LDS line) ----
    if (!__all(pm <= mreg + 8.0f)) {
      const float mn = fmaxf(mreg, pm);
      const float sc = fexp2(mreg - mn);
      ls *= sc;
      mreg = mn;
      scl[w][l31] = sc;
#pragma unroll
      for (int r = 0; r < 16; ++r) {
        const int il = (r & 3) + 8 * (r >> 2) + 4 * hi;
        const float scr = scl[w][il];
        o0[r] *= scr; o1[r] *= scr;
      }
    }

    // ---- exp2 in place (scores pre-scaled by log2 e) ----
#pragma unroll
    for (int r = 0; r < 16; ++r) s[r] = fexp2(s[r] - mreg);
    {
      float l0 = (s[0] + s[4]) + (s[8] + s[12]);
      float l1 = (s[1] + s[5]) + (s[9] + s[13]);
      float l2 = (s[2] + s[6]) + (s[10] + s[14]);
      float l3 = (s[3] + s[7]) + (s[11] + s[15]);
      ls += (l0 + l1) + (l2 + l3);
    }

    // ---- in-register P repack (r4 chain, proven by r4==r5) ----
    f16x8 pfr[2];
    {
      unsigned a0 = pkf16(s[0], s[1]),  b0 = pkf16(s[4], s[5]);
      unsigned a1 = pkf16(s[2], s[3]),  b1 = pkf16(s[6], s[7]);
      plswap(a0, b0); plswap(a1, b1);
      u32x4 t; t[0] = a0; t[1] = a1; t[2] = b0; t[3] = b1;
      pfr[0] = __builtin_bit_cast(f16x8, t);
      unsigned a2 = pkf16(s[8], s[9]),   b2 = pkf16(s[12], s[13]);
      unsigned a3 = pkf16(s[10], s[11]), b3 = pkf16(s[14], s[15]);
      plswap(a2, b2); plswap(a3, b3);
      t[0] = a2; t[1] = a3; t[2] = b2; t[3] = b3;
      pfr[1] = __builtin_bit_cast(f16x8, t);
    }

    // ---- PV ----
    __builtin_amdgcn_s_setprio(1);
#pragma unroll
    for (int kk = 0; kk < 2; ++kk) {
      o0 = __builtin_amdgcn_mfma_f32_32x32x16_f16(pfr[kk], kt0[kk], o0, 0, 0, 0);
      o1 = __builtin_amdgcn_mfma_f32_32x32x16_f16(pfr[kk], kt1[kk], o1, 0, 0, 0);
    }
    __builtin_amdgcn_s_setprio(0);
  }

  // ---- flash merge of the two j-halves ----
  mM[i_sub][jh][l31]  = mreg;                       // both hi halves: same value
  lsM[i_sub][jh][l31] = ls + __shfl_xor(ls, 32);
  __syncthreads();

  if (jh == 1) {
    // wave B: scale own O to the combined max, park in LDS
#pragma unroll
    for (int r = 0; r < 16; ++r) {
      const int il = (r & 3) + 8 * (r >> 2) + 4 * hi;
      const float mS = fmaxf(mM[i_sub][0][il], mM[i_sub][1][il]);
      const float f = fexp2(mM[i_sub][1][il] - mS);
      obuf[i_sub][r][lane]      = o0[r] * f;
      obuf[i_sub][r + 16][lane] = o1[r] * f;
    }
  }
  __syncthreads();
  if (jh == 0) {
    // wave A: combine, normalize, store
#pragma unroll
    for (int r = 0; r < 16; ++r) {
      const int il = (r & 3) + 8 * (r >> 2) + 4 * hi;
      const float mA = mM[i_sub][0][il], mB = mM[i_sub][1][il];
      const float mS = fmaxf(mA, mB);
      const float fA = fexp2(mA - mS);
      const float fB = fexp2(mB - mS);
      const float lsS = lsM[i_sub][0][il] * fA + lsM[i_sub][1][il] * fB;
      const float inv = 1.0f / lsS;
      const size_t rowb = ((size_t)bh * NTOK + i0 + il) * HD;
      out[rowb + l31]      = (o0[r] * fA + obuf[i_sub][r][lane]) * inv;
      out[rowb + 32 + l31] = (o1[r] * fA + obuf[i_sub][r + 16][lane]) * inv;
    }
  }
}

extern "C" void kernel_launch(void* const* d_in, const int* in_sizes, int n_in,
                              void* d_out, int out_size, void* d_ws, size_t ws_size,
                              hipStream_t stream) {
  const float* x  = (const float*)d_in[0];
  const float* Wk = (const float*)d_in[1];
  const float* Wq = (const float*)d_in[2];
  // d_in[3] (Wv) is dead code in the reference — never read.
  float* out = (float*)d_out;

  // ws (f16 elems): [xb|Qp: 8388608][Wkb: 1048576][Wqb: 1048576]
  //                 [Kb: 8388608][Qb|KTp: 8388608]
  _Float16* xb  = (_Float16*)d_ws;
  _Float16* Qp  = xb;
  _Float16* Wkb = xb + (size_t)8388608;
  _Float16* Wqb = Wkb + (size_t)1048576;
  _Float16* Kb  = Wqb + (size_t)1048576;
  _Float16* Qb  = Kb + (size_t)8388608;
  _Float16* KTp = Qb;

  cvt_f32_f16<<<8192, 256, 0, stream>>>(x, xb, 2097152, 1.0f);
  cvt_w<<<dim3(1024, 2), 256, 0, stream>>>(Wk, Wq, Wkb, Wqb);

  dim3 ggrid(MROWS / 128, DMODEL / 128, 2);
  gemm_f16<<<ggrid, 256, 0, stream>>>(xb, Wkb, Wqb, Kb, Qb);

  pack_qkt<<<dim3(2048, 2), 256, 0, stream>>>(Qb, Kb, Qp, KTp);

  attn_mfma<<<2048, 256, 0, stream>>>(Kb, Qp, KTp, out);
}